// Round 1
// 1299.917 us; speedup vs baseline: 1.1846x; 1.1846x over previous
//
#include <hip/hip_runtime.h>
#include <hip/hip_bf16.h>

typedef __hip_bfloat16 bf16;
typedef float f32x2 __attribute__((ext_vector_type(2)));

#define NB_B 4
#define N 20000
#define E 640000
#define F 64
#define HC 128   // conv1 heads*ch
#define ED 16
#define CH 16
#define NT 32    // nodes per tile in node-transform kernels
#define TB1 64   // edge tile, gather1
#define TB2 16   // edge tile per slot, gather23

__device__ __forceinline__ float clampf(float v, float lo, float hi){ return fminf(fmaxf(v, lo), hi); }
__device__ __forceinline__ float ldv(const float* p, size_t i){ return p[i]; }
__device__ __forceinline__ float ldv(const bf16*  p, size_t i){ return __bfloat162float(p[i]); }
__device__ __forceinline__ void  stv(float* p, size_t i, float v){ p[i] = v; }
__device__ __forceinline__ void  stv(bf16*  p, size_t i, float v){ p[i] = __float2bfloat16(v); }
__device__ __forceinline__ unsigned packbf(float lo, float hi){
  bf16 a = __float2bfloat16(lo), b = __float2bfloat16(hi);
  return (unsigned)(*(unsigned short*)&a) | ((unsigned)(*(unsigned short*)&b) << 16);
}
__device__ __forceinline__ float unpl(unsigned u){ return __uint_as_float(u << 16); }
__device__ __forceinline__ float unph(unsigned u){ return __uint_as_float(u & 0xffff0000u); }
__device__ __forceinline__ f32x2 mk2(float a, float b){ f32x2 r; r.x = a; r.y = b; return r; }

// 16-lane (DPP row) all-reduce sum: pure VALU, replaces ds_swizzle-based __shfl_xor chain.
// row_ror:n ctrl = 0x120|n. Rotation butterfly 8,4,2,1 -> every lane holds the 16-lane sum.
__device__ __forceinline__ float rsum16(float x){
  x += __int_as_float(__builtin_amdgcn_update_dpp(0, __float_as_int(x), 0x128, 0xf, 0xf, true));
  x += __int_as_float(__builtin_amdgcn_update_dpp(0, __float_as_int(x), 0x124, 0xf, 0xf, true));
  x += __int_as_float(__builtin_amdgcn_update_dpp(0, __float_as_int(x), 0x122, 0xf, 0xf, true));
  x += __int_as_float(__builtin_amdgcn_update_dpp(0, __float_as_int(x), 0x121, 0xf, 0xf, true));
  return x;
}

// ---------------- dtype detector: f32 inputs (flag=1) vs bf16 (flag=0) ----------------
__global__ __launch_bounds__(256) void k_detect(const unsigned short* __restrict__ xu, int* __restrict__ flag){
  __shared__ int cnt[256];
  int tid = threadIdx.x;
  unsigned short lo = xu[2*tid];
  bf16 h = *(const bf16*)&lo;
  float v = fabsf(__bfloat162float(h));
  cnt[tid] = (v > 1e4f || (v != 0.f && v < 1e-4f)) ? 1 : 0;
  __syncthreads();
  for (int s=128; s>0; s>>=1){ if (tid<s) cnt[tid]+=cnt[tid+s]; __syncthreads(); }
  if (tid==0) *flag = (cnt[0] > 64) ? 1 : 0;
}

// ---------------- CSR build: histogram -> scan -> scatter ----------------
__global__ __launch_bounds__(256) void k_hist(const int* __restrict__ ei, int* __restrict__ cnt, int b0){
  int z = blockIdx.z, b = b0 + z;
  int e = blockIdx.x*256 + threadIdx.x;
  int d = ei[((size_t)b*2+1)*E + e];
  atomicAdd(&cnt[z*N + d], 1);
}

__global__ __launch_bounds__(256) void k_scan(const int* __restrict__ cnt, int* __restrict__ rowptr,
                                              int* __restrict__ cursor){
  int z = blockIdx.z, tid = threadIdx.x;
  const int* c = cnt + (size_t)z*N;
  int* rp = rowptr + (size_t)z*(N+1);
  int* cu = cursor + (size_t)z*N;
  __shared__ int buf[256];
  __shared__ int carry;
  if (tid==0) carry = 0;
  __syncthreads();
  for (int base=0; base<N; base+=256){
    int idx = base + tid;
    int v = (idx < N) ? c[idx] : 0;
    buf[tid] = v; __syncthreads();
    for (int off=1; off<256; off<<=1){
      int t = (tid >= off) ? buf[tid-off] : 0;
      __syncthreads();
      buf[tid] += t;
      __syncthreads();
    }
    int incl = buf[tid];
    int chunk_total = buf[255];
    int out = carry + incl - v;
    if (idx < N){ rp[idx] = out; cu[idx] = out; }
    __syncthreads();
    if (tid==0) carry += chunk_total;
    __syncthreads();
  }
  if (tid==0) rp[N] = carry;
}

__global__ __launch_bounds__(256) void k_scatter(const int* __restrict__ ei, int* __restrict__ cursor,
                                                 int2* __restrict__ csr, int b0){
  int z = blockIdx.z, b = b0 + z;
  int e = blockIdx.x*256 + threadIdx.x;
  int s = ei[((size_t)b*2+0)*E + e];
  int d = ei[((size_t)b*2+1)*E + e];
  int pos = atomicAdd(&cursor[z*N + d], 1);
  csr[(size_t)z*E + pos] = make_int2(s, e);
}

// ---------------- conv1 node transform: 32-node tile ----------------
// __shared__ hoisted to the __global__ wrapper: declaring it inside each template
// instantiation allocated LDS for BOTH dtype branches (2x waste, halved occupancy).
template<typename T>
__device__ __forceinline__ void node1_body(const T* x, const T* Wl, const T* Wr,
                                           float* xl1, float* xr1, int b0,
                                           float (*xs)[F+1]){
  int z = blockIdx.z, b = b0 + z;
  int node0 = blockIdx.x*NT;
  for (int i=threadIdx.x; i<NT*F; i+=256){
    int n = i>>6, k = i&63;
    xs[n][k] = ldv(x, ((size_t)b*N + node0 + n)*F + k);
  }
  __syncthreads();
  int mat = threadIdx.x >> 7, c = threadIdx.x & 127;
  const T* W = mat ? Wr : Wl;
  float acc[NT];
  #pragma unroll
  for (int n=0;n<NT;n++) acc[n]=0.f;
  #pragma unroll 4
  for (int k=0;k<F;k++){
    float wv = ldv(W, (size_t)k*HC + c);
    #pragma unroll
    for (int n=0;n<NT;n++) acc[n] += xs[n][k]*wv;
  }
  float* outp = mat ? xr1 : xl1;
  #pragma unroll
  for (int n=0;n<NT;n++)
    outp[((size_t)z*N + node0 + n)*HC + c] = clampf(acc[n], -1e4f, 1e4f);
}
__global__ __launch_bounds__(256) void k_node1(const void* x, const void* Wl, const void* Wr,
    float* xl1, float* xr1, const int* flag, int b0){
  __shared__ float xs[NT][F+1];
  if (*flag) node1_body((const float*)x,(const float*)Wl,(const float*)Wr,xl1,xr1,b0,xs);
  else       node1_body((const bf16*) x,(const bf16*) Wl,(const bf16*) Wr,xl1,xr1,b0,xs);
}

// ---------------- pack conv1 node features: (c, c+64) bf16 pairs ----------------
__global__ __launch_bounds__(256) void k_pack1(const float* __restrict__ xl1, const float* __restrict__ xr1,
    unsigned* __restrict__ xl1p, unsigned* __restrict__ xr1p){
  int z = blockIdx.z;
  size_t t = (size_t)blockIdx.x*256 + threadIdx.x;     // over N*64
  size_t n = t >> 6; int p = (int)(t & 63);
  size_t base = ((size_t)z*N + n)*HC;
  xl1p[((size_t)z*N + n)*64 + p] = packbf(xl1[base + p], xl1[base + p + 64]);
  xr1p[((size_t)z*N + n)*64 + p] = packbf(xr1[base + p], xr1[base + p + 64]);
}

// ---------------- conv1 fused gather: wave-per-node, packed-f32 channel pairs ----------------
template<typename T>
__device__ __forceinline__ void gather1_body(const int* rowptr, const int2* csr,
    const T* ea, const T* We, const T* att, const T* b1,
    const unsigned* xl1p, const unsigned* xr1p, float* hx, int b0,
    int2 (*sse)[TB1], float (*eas)[TB1][16]){
  int z = blockIdx.z, b = b0 + z;
  int wid = threadIdx.x >> 6, lane = threadIdx.x & 63;
  int node = blockIdx.x*4 + wid;
  int rs = rowptr[(size_t)z*(N+1) + node];
  int re = rowptr[(size_t)z*(N+1) + node + 1];
  unsigned xru = xr1p[((size_t)z*N + node)*64 + lane];
  f32x2 xr2 = mk2(unpl(xru), unph(xru));
  f32x2 w[ED];
  #pragma unroll
  for (int j=0;j<ED;j++) w[j] = mk2(ldv(We, (size_t)j*HC + lane), ldv(We, (size_t)j*HC + lane + 64));
  f32x2 attv = mk2(ldv(att, (size_t)lane), ldv(att, (size_t)lane + 64));
  f32x2 acc = mk2(0.f,0.f), den = mk2(0.f,0.f);
  const unsigned* xlp = xl1p + (size_t)z*N*64;
  for (int base = rs; base < re; base += TB1){
    int m = re - base; if (m > TB1) m = TB1;
    if (lane < m) sse[wid][lane] = csr[(size_t)z*E + base + lane];
    for (int i=lane; i<m*ED; i+=64){
      int e = sse[wid][i>>4].y;
      eas[wid][i>>4][i&15] = ldv(ea, ((size_t)b*E + e)*ED + (i&15));
    }
    // prefetch-by-1: overlap the gathered node-feature load with previous edge's math
    unsigned xv = xlp[(size_t)sse[wid][0].x*64 + lane];
    for (int i=0;i<m;i++){
      unsigned xcur = xv;
      if (i+1 < m) xv = xlp[(size_t)sse[wid][i+1].x*64 + lane];
      f32x2 xl = mk2(unpl(xcur), unph(xcur));
      float ev[16];
      const float4* er = (const float4*)eas[wid][i];
      *(float4*)&ev[0]  = er[0];
      *(float4*)&ev[4]  = er[1];
      *(float4*)&ev[8]  = er[2];
      *(float4*)&ev[12] = er[3];
      f32x2 g = xl + xr2;
      #pragma unroll
      for (int j=0;j<ED;j++) g += w[j]*ev[j];        // v_pk_fma_f32
      f32x2 lr;
      lr.x = fmaxf(g.x,0.f) + 0.2f*fminf(g.x,0.f);
      lr.y = fmaxf(g.y,0.f) + 0.2f*fminf(g.y,0.f);
      f32x2 v = lr*attv;
      float vL = rsum16(v.x);
      float vH = rsum16(v.y);
      f32x2 ex = mk2(__expf(clampf(vL,-60.f,60.f)), __expf(clampf(vH,-60.f,60.f)));
      den += ex;
      acc += ex*xl;
    }
  }
  float hL = acc.x/(den.x + 1e-16f) + ldv(b1, (size_t)lane);
  float hH = acc.y/(den.y + 1e-16f) + ldv(b1, (size_t)lane + 64);
  hL = hL>0.f ? hL : expm1f(hL);
  hH = hH>0.f ? hH : expm1f(hH);
  hx[((size_t)z*N + node)*HC + lane]      = hL;
  hx[((size_t)z*N + node)*HC + lane + 64] = hH;
}
__global__ __launch_bounds__(256) void k_gather1(const int* rowptr, const int2* csr,
    const void* ea, const void* We, const void* att, const void* b1,
    const unsigned* xl1p, const unsigned* xr1p, float* hx, const int* flag, int b0){
  __shared__ int2 sse[4][TB1];
  __shared__ float eas[4][TB1][16];
  if (*flag) gather1_body(rowptr,csr,(const float*)ea,(const float*)We,(const float*)att,(const float*)b1,xl1p,xr1p,hx,b0,sse,eas);
  else       gather1_body(rowptr,csr,(const bf16*) ea,(const bf16*) We,(const bf16*) att,(const bf16*) b1,xl1p,xr1p,hx,b0,sse,eas);
}

// ---------------- conv2/conv3 node transforms: 32-node tile ----------------
template<typename T>
__device__ __forceinline__ void node2_body(const float* hx, const float* xl1,
    const T* W2l, const T* W2r, const T* W3l, const T* W3r,
    float* xl2, float* xr2, float* xl3, float* xr3, int b0,
    float (*hv)[HC+1], float (*sv)[HC+1]){
  int z = blockIdx.z;
  int node0 = blockIdx.x*NT;
  for (int i=threadIdx.x; i<NT*HC; i+=256){
    int n = i>>7, k = i&127;
    size_t o = ((size_t)z*N + node0 + n)*HC + k;
    float h = hx[o];
    hv[n][k] = h;
    sv[n][k] = h + xl1[o];            // hs = hx + skip(=xl1)
  }
  __syncthreads();
  int o = threadIdx.x & 63;
  int mat = o >> 4, c = o & 15;
  int g = threadIdx.x >> 6;
  const T* W = (mat==0)? W2l : (mat==1)? W2r : (mat==2)? W3l : W3r;
  float (*src)[HC+1] = (mat<2)? hv : sv;
  float acc[8];
  #pragma unroll
  for (int j=0;j<8;j++) acc[j]=0.f;
  #pragma unroll 4
  for (int k=0;k<HC;k++){
    float wv = ldv(W, (size_t)k*CH + c);
    #pragma unroll
    for (int j=0;j<8;j++) acc[j] += src[g*8+j][k]*wv;
  }
  float* outp = (mat==0)? xl2 : (mat==1)? xr2 : (mat==2)? xl3 : xr3;
  #pragma unroll
  for (int j=0;j<8;j++)
    outp[((size_t)z*N + node0 + g*8 + j)*CH + c] = clampf(acc[j], -1e4f, 1e4f);
}
__global__ __launch_bounds__(256) void k_node2(const float* hx, const float* xl1,
    const void* W2l, const void* W2r, const void* W3l, const void* W3r,
    float* xl2, float* xr2, float* xl3, float* xr3, const int* flag, int b0){
  __shared__ float hv[NT][HC+1];
  __shared__ float sv[NT][HC+1];
  if (*flag) node2_body(hx,xl1,(const float*)W2l,(const float*)W2r,(const float*)W3l,(const float*)W3r,xl2,xr2,xl3,xr3,b0,hv,sv);
  else       node2_body(hx,xl1,(const bf16*) W2l,(const bf16*) W2r,(const bf16*) W3l,(const bf16*) W3r,xl2,xr2,xl3,xr3,b0,hv,sv);
}

// ---------------- pack conv2/3 node features: (xl2,xl3) and (xr2,xr3) bf16 pairs ----------------
__global__ __launch_bounds__(256) void k_pack2(const float* __restrict__ xl2, const float* __restrict__ xr2,
    const float* __restrict__ xl3, const float* __restrict__ xr3,
    unsigned* __restrict__ xl23p, unsigned* __restrict__ xr23p){
  int z = blockIdx.z;
  size_t t = (size_t)blockIdx.x*256 + threadIdx.x;     // over N*16
  size_t o = (size_t)z*N*CH + t;
  xl23p[o] = packbf(xl2[o], xl3[o]);
  xr23p[o] = packbf(xr2[o], xr3[o]);
}

// ---------------- conv2+conv3 fused gather + linear + LayerNorm + store ----------------
// Restructured: 16 lanes per node (was 32); each lane packs (conv2, conv3) in f32x2,
// removing the duplicated xl23p loads / edge dots of the old q-split halves.
template<typename T>
__device__ __forceinline__ void gather23_body(const int* rowptr, const int2* csr,
    const T* ea, const T* We2, const T* We3, const T* att2, const T* att3,
    const T* b2, const T* b3, const T* linW, const T* linb, const T* lng, const T* lnb,
    const unsigned* xl23p, const unsigned* xr23p,
    T* out, int b0, int2 (*sse)[TB2], float (*eas)[TB2][16]){
  int z = blockIdx.z, b = b0 + z;
  int slot = threadIdx.x >> 4;            // 16 slots of 16 lanes
  int node = blockIdx.x*16 + slot;
  int c = threadIdx.x & 15;
  int rs = rowptr[(size_t)z*(N+1) + node];
  int re = rowptr[(size_t)z*(N+1) + node + 1];
  unsigned xru = xr23p[((size_t)z*N + node)*CH + c];
  f32x2 xr2 = mk2(unpl(xru), unph(xru));  // (conv2, skip-conv)
  f32x2 w[ED];
  #pragma unroll
  for (int j=0;j<ED;j++) w[j] = mk2(ldv(We2,(size_t)j*CH+c), ldv(We3,(size_t)j*CH+c));
  f32x2 attv = mk2(ldv(att2,(size_t)c), ldv(att3,(size_t)c));
  f32x2 acc = mk2(0.f,0.f), den = mk2(0.f,0.f);
  const unsigned* xlp = xl23p + (size_t)z*N*CH;
  for (int base = rs; base < re; base += TB2){
    int m = re - base; if (m > TB2) m = TB2;
    if (c < m) sse[slot][c] = csr[(size_t)z*E + base + c];
    for (int i=c; i<m*ED; i+=16){
      int e = sse[slot][i>>4].y;
      eas[slot][i>>4][i&15] = ldv(ea, ((size_t)b*E + e)*ED + (i&15));
    }
    unsigned xv = xlp[(size_t)sse[slot][0].x*CH + c];
    for (int i=0;i<m;i++){
      unsigned xcur = xv;
      if (i+1 < m) xv = xlp[(size_t)sse[slot][i+1].x*CH + c];
      f32x2 xl = mk2(unpl(xcur), unph(xcur));
      float ev[16];
      const float4* er = (const float4*)eas[slot][i];
      *(float4*)&ev[0]  = er[0];
      *(float4*)&ev[4]  = er[1];
      *(float4*)&ev[8]  = er[2];
      *(float4*)&ev[12] = er[3];
      f32x2 g = xl + xr2;
      #pragma unroll
      for (int j=0;j<ED;j++) g += w[j]*ev[j];
      f32x2 lr;
      lr.x = fmaxf(g.x,0.f) + 0.2f*fminf(g.x,0.f);
      lr.y = fmaxf(g.y,0.f) + 0.2f*fminf(g.y,0.f);
      f32x2 v = lr*attv;
      float v2 = rsum16(v.x);
      float v3 = rsum16(v.y);
      f32x2 ex = mk2(__expf(clampf(v2,-60.f,60.f)), __expf(clampf(v3,-60.f,60.f)));
      den += ex;
      acc += ex*xl;
    }
  }
  float x1 = acc.x/(den.x + 1e-16f) + ldv(b2,(size_t)c);   // conv2 output
  float x3 = acc.y/(den.y + 1e-16f) + ldv(b3,(size_t)c);   // skip-conv output
  // linear on skip-conv: x2[c] = sum_j x3[j]*linW[c][j] + linb[c]
  float x2 = 0.f;
  #pragma unroll
  for (int j=0;j<16;j++) x2 += __shfl(x3, j, 16) * ldv(linW, (size_t)c*16 + j);
  x2 += ldv(linb,(size_t)c);
  float y = clampf(x1, -1e6f, 1e6f) + clampf(x2, -1e6f, 1e6f);
  float mu = rsum16(y)*(1.f/16.f);
  float dv = y - mu;
  float var = rsum16(dv*dv)*(1.f/16.f);
  float o = dv*rsqrtf(var + 1e-5f)*ldv(lng,(size_t)c) + ldv(lnb,(size_t)c);
  stv(out, ((size_t)(b0+z)*N + node)*16 + c, o);
}
__global__ __launch_bounds__(256) void k_gather23(const int* rowptr, const int2* csr,
    const void* ea, const void* We2, const void* We3, const void* att2, const void* att3,
    const void* b2, const void* b3, const void* linW, const void* linb, const void* lng, const void* lnb,
    const unsigned* xl23p, const unsigned* xr23p,
    void* out, const int* flag, int b0){
  __shared__ int2 sse[16][TB2];
  __shared__ float eas[16][TB2][16];
  if (*flag) gather23_body(rowptr,csr,(const float*)ea,(const float*)We2,(const float*)We3,(const float*)att2,(const float*)att3,
                           (const float*)b2,(const float*)b3,(const float*)linW,(const float*)linb,(const float*)lng,(const float*)lnb,
                           xl23p,xr23p,(float*)out,b0,sse,eas);
  else       gather23_body(rowptr,csr,(const bf16*) ea,(const bf16*) We2,(const bf16*) We3,(const bf16*) att2,(const bf16*) att3,
                           (const bf16*) b2,(const bf16*) b3,(const bf16*) linW,(const bf16*) linb,(const bf16*) lng,(const bf16*) lnb,
                           xl23p,xr23p,(bf16*) out,b0,sse,eas);
}

// ---------------- workspace layout ----------------
struct WSP {
  int* flag;
  int *cnt, *cursor, *rowptr; int2* csr;
  float *xl1,*xr1,*hx,*xl2,*xr2,*xl3,*xr3;
  unsigned *xl1p,*xr1p,*xl23p,*xr23p;
  size_t total;
};
static WSP mkws(char* base, int nb){
  WSP w; size_t off = 0;
  auto A = [&](size_t bytes)->char*{ char* p = base ? base + off : (char*)0; off = (off + bytes + 255) & ~(size_t)255; return p; };
  w.flag   = (int*)     A(256);
  w.cnt    = (int*)     A((size_t)nb*N*4);
  w.cursor = (int*)     A((size_t)nb*N*4);
  w.rowptr = (int*)     A((size_t)nb*(N+1)*4);
  w.csr    = (int2*)    A((size_t)nb*E*8);
  w.xl1    = (float*)   A((size_t)nb*N*HC*4);
  w.xr1    = (float*)   A((size_t)nb*N*HC*4);
  w.hx     = (float*)   A((size_t)nb*N*HC*4);
  w.xl2    = (float*)   A((size_t)nb*N*CH*4);
  w.xr2    = (float*)   A((size_t)nb*N*CH*4);
  w.xl3    = (float*)   A((size_t)nb*N*CH*4);
  w.xr3    = (float*)   A((size_t)nb*N*CH*4);
  w.xl1p   = (unsigned*)A((size_t)nb*N*64*4);
  w.xr1p   = (unsigned*)A((size_t)nb*N*64*4);
  w.xl23p  = (unsigned*)A((size_t)nb*N*CH*4);
  w.xr23p  = (unsigned*)A((size_t)nb*N*CH*4);
  w.total = off;
  return w;
}

extern "C" void kernel_launch(void* const* d_in, const int* in_sizes, int n_in,
                              void* d_out, int out_size, void* d_ws, size_t ws_size,
                              hipStream_t stream){
  const void* x    = d_in[0];
  const void* ea   = d_in[1];
  const int*  ei   = (const int*)d_in[2];
  const void* c1Wl = d_in[3], *c1Wr = d_in[4], *c1We = d_in[5];
  const void* c1att= d_in[6], *c1b  = d_in[7];
  const void* c2Wl = d_in[8], *c2Wr = d_in[9], *c2We = d_in[10];
  const void* c2att= d_in[11],*c2b  = d_in[12];
  const void* sWl  = d_in[13],*sWr  = d_in[14],*sWe  = d_in[15];
  const void* satt = d_in[16],*sb   = d_in[17];
  const void* linW = d_in[18],*linb = d_in[19];
  const void* lng  = d_in[20],*lnb  = d_in[21];

  auto run = [&](int b0, int nb){
    WSP w = mkws((char*)d_ws, nb);
    hipMemsetAsync(w.cnt, 0, (size_t)nb*N*4, stream);
    // CSR build (shared by all three convs)
    k_hist   <<<dim3(E/256,1,nb),   256,0,stream>>>(ei, w.cnt, b0);
    k_scan   <<<dim3(1,1,nb),       256,0,stream>>>(w.cnt, w.rowptr, w.cursor);
    k_scatter<<<dim3(E/256,1,nb),   256,0,stream>>>(ei, w.cursor, w.csr, b0);
    // conv1
    k_node1  <<<dim3(N/NT,1,nb),    256,0,stream>>>(x, c1Wl, c1Wr, w.xl1, w.xr1, w.flag, b0);
    k_pack1  <<<dim3(N*64/256,1,nb),256,0,stream>>>(w.xl1, w.xr1, w.xl1p, w.xr1p);
    k_gather1<<<dim3(N/4,1,nb),     256,0,stream>>>(w.rowptr, w.csr, ea, c1We, c1att, c1b,
                                                    w.xl1p, w.xr1p, w.hx, w.flag, b0);
    // conv2 + skip-conv
    k_node2  <<<dim3(N/NT,1,nb),    256,0,stream>>>(w.hx, w.xl1, c2Wl, c2Wr, sWl, sWr,
                                                    w.xl2, w.xr2, w.xl3, w.xr3, w.flag, b0);
    k_pack2  <<<dim3(N*16/256,1,nb),256,0,stream>>>(w.xl2, w.xr2, w.xl3, w.xr3, w.xl23p, w.xr23p);
    k_gather23<<<dim3(N/16,1,nb),   256,0,stream>>>(w.rowptr, w.csr, ea, c2We, sWe, c2att, satt,
                                                    c2b, sb, linW, linb, lng, lnb,
                                                    w.xl23p, w.xr23p, d_out, w.flag, b0);
  };

  {
    WSP w0 = mkws((char*)d_ws, 1);
    k_detect<<<1,256,0,stream>>>((const unsigned short*)x, w0.flag);
  }

  WSP probe = mkws((char*)0, NB_B);
  if (ws_size >= probe.total){
    run(0, NB_B);                          // single batched pass
  } else {
    for (int g=0; g<NB_B; ++g) run(g, 1);  // per-graph fallback
  }
}

// Round 2
// 1130.223 us; speedup vs baseline: 1.3624x; 1.1501x over previous
//
#include <hip/hip_runtime.h>
#include <hip/hip_bf16.h>

typedef __hip_bfloat16 bf16;
typedef float f32x2 __attribute__((ext_vector_type(2)));

#define NB_B 4
#define N 20000
#define E 640000
#define F 64
#define HC 128   // conv1 heads*ch
#define ED 16
#define CH 16
#define NT 32    // nodes per tile in node-transform kernels
#define TB1 64   // edge tile, gather1
#define TB2 16   // edge tile per slot, gather23

__device__ __forceinline__ float clampf(float v, float lo, float hi){ return fminf(fmaxf(v, lo), hi); }
__device__ __forceinline__ float ldv(const float* p, size_t i){ return p[i]; }
__device__ __forceinline__ float ldv(const bf16*  p, size_t i){ return __bfloat162float(p[i]); }
__device__ __forceinline__ void  stv(float* p, size_t i, float v){ p[i] = v; }
__device__ __forceinline__ void  stv(bf16*  p, size_t i, float v){ p[i] = __float2bfloat16(v); }
__device__ __forceinline__ unsigned short tobf(float v){ bf16 b = __float2bfloat16(v); return *(unsigned short*)&b; }
__device__ __forceinline__ float unpl(unsigned u){ return __uint_as_float(u << 16); }
__device__ __forceinline__ float unph(unsigned u){ return __uint_as_float(u & 0xffff0000u); }
__device__ __forceinline__ f32x2 mk2(float a, float b){ f32x2 r; r.x = a; r.y = b; return r; }

// 16-lane (DPP row) all-reduce sum: pure VALU (row_ror butterfly 8,4,2,1).
__device__ __forceinline__ float rsum16(float x){
  x += __int_as_float(__builtin_amdgcn_update_dpp(0, __float_as_int(x), 0x128, 0xf, 0xf, true));
  x += __int_as_float(__builtin_amdgcn_update_dpp(0, __float_as_int(x), 0x124, 0xf, 0xf, true));
  x += __int_as_float(__builtin_amdgcn_update_dpp(0, __float_as_int(x), 0x122, 0xf, 0xf, true));
  x += __int_as_float(__builtin_amdgcn_update_dpp(0, __float_as_int(x), 0x121, 0xf, 0xf, true));
  return x;
}

// ---------------- dtype detector: f32 inputs (flag=1) vs bf16 (flag=0) ----------------
__global__ __launch_bounds__(256) void k_detect(const unsigned short* __restrict__ xu, int* __restrict__ flag){
  __shared__ int cnt[256];
  int tid = threadIdx.x;
  unsigned short lo = xu[2*tid];
  bf16 h = *(const bf16*)&lo;
  float v = fabsf(__bfloat162float(h));
  cnt[tid] = (v > 1e4f || (v != 0.f && v < 1e-4f)) ? 1 : 0;
  __syncthreads();
  for (int s=128; s>0; s>>=1){ if (tid<s) cnt[tid]+=cnt[tid+s]; __syncthreads(); }
  if (tid==0) *flag = (cnt[0] > 64) ? 1 : 0;
}

// ---------------- CSR build: histogram -> scan -> scatter(+ea reorder) ----------------
__global__ __launch_bounds__(256) void k_hist(const int* __restrict__ ei, int* __restrict__ cnt, int b0){
  int z = blockIdx.z, b = b0 + z;
  int e = blockIdx.x*256 + threadIdx.x;
  int d = ei[((size_t)b*2+1)*E + e];
  atomicAdd(&cnt[z*N + d], 1);
}

// thread-serial chunk scan: 79 elems/thread, one 256-wide block scan. ~16 barriers total.
__global__ __launch_bounds__(256) void k_scan(const int* __restrict__ cnt, int* __restrict__ rowptr,
                                              int* __restrict__ cursor){
  int z = blockIdx.z, tid = threadIdx.x;
  const int* c = cnt + (size_t)z*N;
  int* rp = rowptr + (size_t)z*(N+1);
  int* cu = cursor + (size_t)z*N;
  const int CHK = (N + 255)/256;
  int lo = tid*CHK; int hi = lo + CHK; if (hi > N) hi = N; if (lo > N) lo = N;
  int s = 0;
  for (int i=lo;i<hi;i++) s += c[i];
  __shared__ int buf[256];
  buf[tid] = s; __syncthreads();
  for (int off=1; off<256; off<<=1){
    int t = (tid>=off) ? buf[tid-off] : 0;
    __syncthreads();
    buf[tid] += t;
    __syncthreads();
  }
  int run = buf[tid] - s;         // exclusive prefix
  for (int i=lo;i<hi;i++){ int v=c[i]; rp[i]=run; cu[i]=run; run += v; }
  if (tid==255) rp[N] = run;
}

// scatter: write src index + copy edge attrs into CSR order (f32, numerically identical).
template<typename T>
__device__ __forceinline__ void scatter_body(const int* ei, int* cursor, int* csr,
                                             const T* ea, float* eacsr, int b0){
  int z = blockIdx.z, b = b0 + z;
  int e = blockIdx.x*256 + threadIdx.x;
  int s = ei[((size_t)b*2+0)*E + e];
  int d = ei[((size_t)b*2+1)*E + e];
  int pos = atomicAdd(&cursor[z*N + d], 1);
  csr[(size_t)z*E + pos] = s;
  float4* dst = (float4*)(eacsr + ((size_t)z*E + pos)*ED);
  const T* sp = ea + ((size_t)b*E + e)*ED;
  #pragma unroll
  for (int g=0; g<4; g++){
    float4 t;
    t.x = ldv(sp, g*4+0); t.y = ldv(sp, g*4+1); t.z = ldv(sp, g*4+2); t.w = ldv(sp, g*4+3);
    dst[g] = t;
  }
}
__global__ __launch_bounds__(256) void k_scatter(const int* ei, int* cursor, int* csr,
    const void* ea, float* eacsr, const int* flag, int b0){
  if (*flag) scatter_body(ei, cursor, csr, (const float*)ea, eacsr, b0);
  else       scatter_body(ei, cursor, csr, (const bf16*) ea, eacsr, b0);
}

// ---------------- conv1 node transform: 32-node tile, writes packed bf16 directly ----------------
template<typename T>
__device__ __forceinline__ void node1_body(const T* x, const T* Wl, const T* Wr,
                                           unsigned* xl1p, unsigned* xr1p, int b0,
                                           float (*xs)[F+4]){
  int z = blockIdx.z, b = b0 + z;
  int node0 = blockIdx.x*NT;
  for (int i=threadIdx.x; i<NT*F; i+=256){
    int n = i>>6, k = i&63;
    xs[n][k] = ldv(x, ((size_t)b*N + node0 + n)*F + k);
  }
  __syncthreads();
  int mat = threadIdx.x >> 7, c = threadIdx.x & 127;
  const T* W = mat ? Wr : Wl;
  float acc[NT];
  #pragma unroll
  for (int n=0;n<NT;n++) acc[n]=0.f;
  for (int k=0;k<F;k+=4){
    float w0 = ldv(W, (size_t)(k+0)*HC + c);
    float w1 = ldv(W, (size_t)(k+1)*HC + c);
    float w2 = ldv(W, (size_t)(k+2)*HC + c);
    float w3 = ldv(W, (size_t)(k+3)*HC + c);
    #pragma unroll
    for (int n=0;n<NT;n++){
      float4 xv = *(const float4*)&xs[n][k];
      acc[n] += xv.x*w0 + xv.y*w1 + xv.z*w2 + xv.w*w3;
    }
  }
  unsigned short* outp = (unsigned short*)(mat ? xr1p : xl1p);
  int half = c>>6, cc = c&63;
  #pragma unroll
  for (int n=0;n<NT;n++){
    float v = clampf(acc[n], -1e4f, 1e4f);
    outp[(((size_t)z*N + node0 + n)*64 + cc)*2 + half] = tobf(v);
  }
}
__global__ __launch_bounds__(256) void k_node1(const void* x, const void* Wl, const void* Wr,
    unsigned* xl1p, unsigned* xr1p, const int* flag, int b0){
  __shared__ float xs[NT][F+4];
  if (*flag) node1_body((const float*)x,(const float*)Wl,(const float*)Wr,xl1p,xr1p,b0,xs);
  else       node1_body((const bf16*) x,(const bf16*) Wl,(const bf16*) Wr,xl1p,xr1p,b0,xs);
}

// ---------------- conv1 fused gather: wave-per-node, streamed ea, prefetch-2, unroll-2 ----------------
template<typename T>
__device__ __forceinline__ void gather1_body(const int* rowptr, const int* csr, const float* eacsr,
    const T* We, const T* att, const T* b1,
    const unsigned* xl1p, const unsigned* xr1p, float* hx, int b0,
    int (*ssrc)[TB1], float (*eas)[TB1][16]){
  int z = blockIdx.z;
  int wid = threadIdx.x >> 6, lane = threadIdx.x & 63;
  int node = blockIdx.x*4 + wid;
  int rs = rowptr[(size_t)z*(N+1) + node];
  int re = rowptr[(size_t)z*(N+1) + node + 1];
  unsigned xru = xr1p[((size_t)z*N + node)*64 + lane];
  f32x2 xr2 = mk2(unpl(xru), unph(xru));
  f32x2 w[ED];
  #pragma unroll
  for (int j=0;j<ED;j++) w[j] = mk2(ldv(We, (size_t)j*HC + lane), ldv(We, (size_t)j*HC + lane + 64));
  f32x2 attv = mk2(ldv(att, (size_t)lane), ldv(att, (size_t)lane + 64));
  f32x2 acc = mk2(0.f,0.f), den = mk2(0.f,0.f);
  const unsigned* xlp = xl1p + (size_t)z*N*64;
  const int* csrz = csr + (size_t)z*E;

  auto edge = [&](int i, unsigned xw){
    f32x2 xl = mk2(unpl(xw), unph(xw));
    float ev[16];
    const float4* er = (const float4*)eas[wid][i];
    *(float4*)&ev[0]  = er[0];
    *(float4*)&ev[4]  = er[1];
    *(float4*)&ev[8]  = er[2];
    *(float4*)&ev[12] = er[3];
    f32x2 g = xl + xr2;
    #pragma unroll
    for (int j=0;j<ED;j++) g += w[j]*ev[j];
    f32x2 lr;
    lr.x = fmaxf(g.x,0.f) + 0.2f*fminf(g.x,0.f);
    lr.y = fmaxf(g.y,0.f) + 0.2f*fminf(g.y,0.f);
    f32x2 v = lr*attv;
    float vL = rsum16(v.x);
    float vH = rsum16(v.y);
    f32x2 ex = mk2(__expf(clampf(vL,-60.f,60.f)), __expf(clampf(vH,-60.f,60.f)));
    den += ex;
    acc += ex*xl;
  };

  for (int base = rs; base < re; base += TB1){
    int m = re - base; if (m > TB1) m = TB1;
    if (lane < m) ssrc[wid][lane] = csrz[base + lane];
    const float4* ep = (const float4*)(eacsr + ((size_t)z*E + base)*ED);
    for (int i4=lane; i4<m*4; i4+=64)
      *(float4*)&eas[wid][i4>>2][(i4&3)*4] = ep[i4];
    // depth-2 gathered-feature prefetch
    unsigned pa = xlp[(unsigned)(ssrc[wid][0]*64 + lane)];
    unsigned pb = (m>1) ? xlp[(unsigned)(ssrc[wid][1]*64 + lane)] : pa;
    int i = 0;
    for (; i+1 < m; i += 2){
      unsigned x0 = pa, x1 = pb;
      int i2 = (i+2 < m) ? i+2 : m-1;
      int i3 = (i+3 < m) ? i+3 : m-1;
      int s2 = ssrc[wid][i2], s3 = ssrc[wid][i3];
      pa = xlp[(unsigned)(s2*64 + lane)];
      pb = xlp[(unsigned)(s3*64 + lane)];
      edge(i, x0);
      edge(i+1, x1);
    }
    if (i < m) edge(i, pa);
  }
  float hL = acc.x/(den.x + 1e-16f) + ldv(b1, (size_t)lane);
  float hH = acc.y/(den.y + 1e-16f) + ldv(b1, (size_t)lane + 64);
  hL = hL>0.f ? hL : expm1f(hL);
  hH = hH>0.f ? hH : expm1f(hH);
  hx[((size_t)z*N + node)*HC + lane]      = hL;
  hx[((size_t)z*N + node)*HC + lane + 64] = hH;
}
__global__ __launch_bounds__(256) void k_gather1(const int* rowptr, const int* csr, const float* eacsr,
    const void* We, const void* att, const void* b1,
    const unsigned* xl1p, const unsigned* xr1p, float* hx, const int* flag, int b0){
  __shared__ int ssrc[4][TB1];
  __shared__ float eas[4][TB1][16];
  if (*flag) gather1_body(rowptr,csr,eacsr,(const float*)We,(const float*)att,(const float*)b1,xl1p,xr1p,hx,b0,ssrc,eas);
  else       gather1_body(rowptr,csr,eacsr,(const bf16*) We,(const bf16*) att,(const bf16*) b1,xl1p,xr1p,hx,b0,ssrc,eas);
}

// ---------------- conv2/conv3 node transforms: 32-node tile, writes packed bf16 directly ----------------
template<typename T>
__device__ __forceinline__ void node2_body(const float* hx, const unsigned* xl1p,
    const T* W2l, const T* W2r, const T* W3l, const T* W3r,
    unsigned* xl23p, unsigned* xr23p, int b0,
    float (*hv)[HC+4], float (*sv)[HC+4]){
  int z = blockIdx.z;
  int node0 = blockIdx.x*NT;
  for (int i=threadIdx.x; i<NT*HC; i+=256){
    int n = i>>7, k = i&127;
    float h = hx[((size_t)z*N + node0 + n)*HC + k];
    unsigned wxl = xl1p[((size_t)z*N + node0 + n)*64 + (k&63)];
    float xv = (k<64) ? unpl(wxl) : unph(wxl);
    hv[n][k] = h;
    sv[n][k] = h + xv;                // hs = hx + skip(=xl1)
  }
  __syncthreads();
  int o = threadIdx.x & 63;
  int mat = o >> 4, c = o & 15;
  int g = threadIdx.x >> 6;
  const T* W = (mat==0)? W2l : (mat==1)? W2r : (mat==2)? W3l : W3r;
  float (*src)[HC+4] = (mat<2)? hv : sv;
  float acc[8];
  #pragma unroll
  for (int j=0;j<8;j++) acc[j]=0.f;
  for (int k=0;k<HC;k+=4){
    float w0 = ldv(W, (size_t)(k+0)*CH + c);
    float w1 = ldv(W, (size_t)(k+1)*CH + c);
    float w2 = ldv(W, (size_t)(k+2)*CH + c);
    float w3 = ldv(W, (size_t)(k+3)*CH + c);
    #pragma unroll
    for (int j=0;j<8;j++){
      float4 xv = *(const float4*)&src[g*8+j][k];
      acc[j] += xv.x*w0 + xv.y*w1 + xv.z*w2 + xv.w*w3;
    }
  }
  unsigned short* arr = (unsigned short*)((mat&1) ? xr23p : xl23p);
  int half = mat>>1;
  #pragma unroll
  for (int j=0;j<8;j++){
    float v = clampf(acc[j], -1e4f, 1e4f);
    arr[(((size_t)z*N + node0 + g*8 + j)*CH + c)*2 + half] = tobf(v);
  }
}
__global__ __launch_bounds__(256) void k_node2(const float* hx, const unsigned* xl1p,
    const void* W2l, const void* W2r, const void* W3l, const void* W3r,
    unsigned* xl23p, unsigned* xr23p, const int* flag, int b0){
  __shared__ float hv[NT][HC+4];
  __shared__ float sv[NT][HC+4];
  if (*flag) node2_body(hx,xl1p,(const float*)W2l,(const float*)W2r,(const float*)W3l,(const float*)W3r,xl23p,xr23p,b0,hv,sv);
  else       node2_body(hx,xl1p,(const bf16*) W2l,(const bf16*) W2r,(const bf16*) W3l,(const bf16*) W3r,xl23p,xr23p,b0,hv,sv);
}

// ---------------- conv2+conv3 fused gather + linear + LayerNorm + store ----------------
template<typename T>
__device__ __forceinline__ void gather23_body(const int* rowptr, const int* csr, const float* eacsr,
    const T* We2, const T* We3, const T* att2, const T* att3,
    const T* b2, const T* b3, const T* linW, const T* linb, const T* lng, const T* lnb,
    const unsigned* xl23p, const unsigned* xr23p,
    T* out, int b0, int (*ssrc)[TB2], float (*eas)[TB2][16]){
  int z = blockIdx.z;
  int slot = threadIdx.x >> 4;            // 16 slots of 16 lanes
  int node = blockIdx.x*16 + slot;
  int c = threadIdx.x & 15;
  int rs = rowptr[(size_t)z*(N+1) + node];
  int re = rowptr[(size_t)z*(N+1) + node + 1];
  unsigned xru = xr23p[((size_t)z*N + node)*CH + c];
  f32x2 xr2 = mk2(unpl(xru), unph(xru));  // (conv2, skip-conv)
  f32x2 w[ED];
  #pragma unroll
  for (int j=0;j<ED;j++) w[j] = mk2(ldv(We2,(size_t)j*CH+c), ldv(We3,(size_t)j*CH+c));
  f32x2 attv = mk2(ldv(att2,(size_t)c), ldv(att3,(size_t)c));
  f32x2 acc = mk2(0.f,0.f), den = mk2(0.f,0.f);
  const unsigned* xlp = xl23p + (size_t)z*N*CH;
  const int* csrz = csr + (size_t)z*E;

  auto edge = [&](int i, unsigned xw){
    f32x2 xl = mk2(unpl(xw), unph(xw));
    float ev[16];
    const float4* er = (const float4*)eas[slot][i];
    *(float4*)&ev[0]  = er[0];
    *(float4*)&ev[4]  = er[1];
    *(float4*)&ev[8]  = er[2];
    *(float4*)&ev[12] = er[3];
    f32x2 g = xl + xr2;
    #pragma unroll
    for (int j=0;j<ED;j++) g += w[j]*ev[j];
    f32x2 lr;
    lr.x = fmaxf(g.x,0.f) + 0.2f*fminf(g.x,0.f);
    lr.y = fmaxf(g.y,0.f) + 0.2f*fminf(g.y,0.f);
    f32x2 v = lr*attv;
    float v2 = rsum16(v.x);
    float v3 = rsum16(v.y);
    f32x2 ex = mk2(__expf(clampf(v2,-60.f,60.f)), __expf(clampf(v3,-60.f,60.f)));
    den += ex;
    acc += ex*xl;
  };

  for (int base = rs; base < re; base += TB2){
    int m = re - base; if (m > TB2) m = TB2;
    if (c < m) ssrc[slot][c] = csrz[base + c];
    const float4* ep = (const float4*)(eacsr + ((size_t)z*E + base)*ED);
    for (int i4=c; i4<m*4; i4+=16)
      *(float4*)&eas[slot][i4>>2][(i4&3)*4] = ep[i4];
    unsigned pa = xlp[(unsigned)(ssrc[slot][0]*CH + c)];
    unsigned pb = (m>1) ? xlp[(unsigned)(ssrc[slot][1]*CH + c)] : pa;
    int i = 0;
    for (; i+1 < m; i += 2){
      unsigned x0 = pa, x1 = pb;
      int i2 = (i+2 < m) ? i+2 : m-1;
      int i3 = (i+3 < m) ? i+3 : m-1;
      int s2 = ssrc[slot][i2], s3 = ssrc[slot][i3];
      pa = xlp[(unsigned)(s2*CH + c)];
      pb = xlp[(unsigned)(s3*CH + c)];
      edge(i, x0);
      edge(i+1, x1);
    }
    if (i < m) edge(i, pa);
  }
  float x1 = acc.x/(den.x + 1e-16f) + ldv(b2,(size_t)c);   // conv2 output
  float x3 = acc.y/(den.y + 1e-16f) + ldv(b3,(size_t)c);   // skip-conv output
  float x2 = 0.f;
  #pragma unroll
  for (int j=0;j<16;j++) x2 += __shfl(x3, j, 16) * ldv(linW, (size_t)c*16 + j);
  x2 += ldv(linb,(size_t)c);
  float y = clampf(x1, -1e6f, 1e6f) + clampf(x2, -1e6f, 1e6f);
  float mu = rsum16(y)*(1.f/16.f);
  float dv = y - mu;
  float var = rsum16(dv*dv)*(1.f/16.f);
  float o = dv*rsqrtf(var + 1e-5f)*ldv(lng,(size_t)c) + ldv(lnb,(size_t)c);
  stv(out, ((size_t)(b0+z)*N + node)*16 + c, o);
}
__global__ __launch_bounds__(256) void k_gather23(const int* rowptr, const int* csr, const float* eacsr,
    const void* We2, const void* We3, const void* att2, const void* att3,
    const void* b2, const void* b3, const void* linW, const void* linb, const void* lng, const void* lnb,
    const unsigned* xl23p, const unsigned* xr23p,
    void* out, const int* flag, int b0){
  __shared__ int ssrc[16][TB2];
  __shared__ float eas[16][TB2][16];
  if (*flag) gather23_body(rowptr,csr,eacsr,(const float*)We2,(const float*)We3,(const float*)att2,(const float*)att3,
                           (const float*)b2,(const float*)b3,(const float*)linW,(const float*)linb,(const float*)lng,(const float*)lnb,
                           xl23p,xr23p,(float*)out,b0,ssrc,eas);
  else       gather23_body(rowptr,csr,eacsr,(const bf16*) We2,(const bf16*) We3,(const bf16*) att2,(const bf16*) att3,
                           (const bf16*) b2,(const bf16*) b3,(const bf16*) linW,(const bf16*) linb,(const bf16*) lng,(const bf16*) lnb,
                           xl23p,xr23p,(bf16*) out,b0,ssrc,eas);
}

// ---------------- workspace layout ----------------
struct WSP {
  int* flag;
  int *cnt, *cursor, *rowptr; int* csr;
  float *eacsr, *hx;
  unsigned *xl1p,*xr1p,*xl23p,*xr23p;
  size_t total;
};
static WSP mkws(char* base, int nb){
  WSP w; size_t off = 0;
  auto A = [&](size_t bytes)->char*{ char* p = base ? base + off : (char*)0; off = (off + bytes + 255) & ~(size_t)255; return p; };
  w.flag   = (int*)     A(256);
  w.cnt    = (int*)     A((size_t)nb*N*4);
  w.cursor = (int*)     A((size_t)nb*N*4);
  w.rowptr = (int*)     A((size_t)nb*(N+1)*4);
  w.csr    = (int*)     A((size_t)nb*E*4);
  w.eacsr  = (float*)   A((size_t)nb*E*ED*4);
  w.hx     = (float*)   A((size_t)nb*N*HC*4);
  w.xl1p   = (unsigned*)A((size_t)nb*N*64*4);
  w.xr1p   = (unsigned*)A((size_t)nb*N*64*4);
  w.xl23p  = (unsigned*)A((size_t)nb*N*CH*4);
  w.xr23p  = (unsigned*)A((size_t)nb*N*CH*4);
  w.total = off;
  return w;
}

extern "C" void kernel_launch(void* const* d_in, const int* in_sizes, int n_in,
                              void* d_out, int out_size, void* d_ws, size_t ws_size,
                              hipStream_t stream){
  const void* x    = d_in[0];
  const void* ea   = d_in[1];
  const int*  ei   = (const int*)d_in[2];
  const void* c1Wl = d_in[3], *c1Wr = d_in[4], *c1We = d_in[5];
  const void* c1att= d_in[6], *c1b  = d_in[7];
  const void* c2Wl = d_in[8], *c2Wr = d_in[9], *c2We = d_in[10];
  const void* c2att= d_in[11],*c2b  = d_in[12];
  const void* sWl  = d_in[13],*sWr  = d_in[14],*sWe  = d_in[15];
  const void* satt = d_in[16],*sb   = d_in[17];
  const void* linW = d_in[18],*linb = d_in[19];
  const void* lng  = d_in[20],*lnb  = d_in[21];

  auto run = [&](int b0, int nb){
    WSP w = mkws((char*)d_ws, nb);
    hipMemsetAsync(w.cnt, 0, (size_t)nb*N*4, stream);
    k_hist   <<<dim3(E/256,1,nb),   256,0,stream>>>(ei, w.cnt, b0);
    k_scan   <<<dim3(1,1,nb),       256,0,stream>>>(w.cnt, w.rowptr, w.cursor);
    k_scatter<<<dim3(E/256,1,nb),   256,0,stream>>>(ei, w.cursor, w.csr, ea, w.eacsr, w.flag, b0);
    // conv1
    k_node1  <<<dim3(N/NT,1,nb),    256,0,stream>>>(x, c1Wl, c1Wr, w.xl1p, w.xr1p, w.flag, b0);
    k_gather1<<<dim3(N/4,1,nb),     256,0,stream>>>(w.rowptr, w.csr, w.eacsr, c1We, c1att, c1b,
                                                    w.xl1p, w.xr1p, w.hx, w.flag, b0);
    // conv2 + skip-conv
    k_node2  <<<dim3(N/NT,1,nb),    256,0,stream>>>(w.hx, w.xl1p, c2Wl, c2Wr, sWl, sWr,
                                                    w.xl23p, w.xr23p, w.flag, b0);
    k_gather23<<<dim3(N/16,1,nb),   256,0,stream>>>(w.rowptr, w.csr, w.eacsr, c2We, sWe, c2att, satt,
                                                    c2b, sb, linW, linb, lng, lnb,
                                                    w.xl23p, w.xr23p, d_out, w.flag, b0);
  };

  {
    WSP w0 = mkws((char*)d_ws, 1);
    k_detect<<<1,256,0,stream>>>((const unsigned short*)x, w0.flag);
  }

  WSP probe = mkws((char*)0, NB_B);
  if (ws_size >= probe.total){
    run(0, NB_B);                          // single batched pass
  } else {
    for (int g=0; g<NB_B; ++g) run(g, 1);  // per-graph fallback
  }
}